// Round 4
// baseline (137.613 us; speedup 1.0000x reference)
//
#include <hip/hip_runtime.h>

#ifndef __has_builtin
#define __has_builtin(x) 0
#endif

__device__ __forceinline__ float fast_rsqrt(float x) {
#if __has_builtin(__builtin_amdgcn_rsqf)
    return __builtin_amdgcn_rsqf(x);     // raw v_rsq_f32
#else
    return rsqrtf(x);
#endif
}

__device__ __forceinline__ float fast_rcp(float x) {
#if __has_builtin(__builtin_amdgcn_rcpf)
    return __builtin_amdgcn_rcpf(x);
#else
    return 1.0f / x;
#endif
}

constexpr int Bc = 2048;   // batch
constexpr int Fc = 256;    // in_features
constexpr int Cc = 256;    // clusters
constexpr int RB = 4;      // batch rows per block
constexpr int NW = 8;      // waves per block (512 threads)
constexpr int JW = Fc / NW; // 32: j-slice per wave

// DIAGNOSTIC ROUND: identical structure to R3, but the j-loop body runs
// REPEAT=5 times WITHOUT resetting acc. num and den both scale by 5, the
// ratio is unchanged (out identical to within fp rounding), nothing is
// dead-code-eliminable, and work is identical on every call (graph-safe).
//   -> kernel time k = (dur_us_R4 - dur_us_R3) / (REPEAT-1)
//   -> if k >~ 8.5us the 5k dispatch rises above the ~40us harness fills
//      and we finally get VALUBusy/Occupancy/FETCH for OUR kernel.
constexpr int REPEAT = 5;

__global__ __launch_bounds__(512, 4)
void clusteringLayer_77154792506116_kernel(const float* __restrict__ x,
                                           const float* __restrict__ mu,
                                           float* __restrict__ out) {
    const int tid  = threadIdx.x;
    const int wv   = tid >> 6;
    const int lane = tid & 63;
    const int b0   = blockIdx.x * RB;

    __shared__ float red[NW][RB][Cc];   // 32 KB partial nums
    __shared__ float denp[NW];          // per-wave den partials

    const int    j0  = __builtin_amdgcn_readfirstlane(wv * JW);  // SGPR
    const float* xp  = x + (size_t)b0 * Fc;                      // scalar base
    const float4* mu4 = (const float4*)mu + lane;                // mu[j][4l..4l+3]

    float4 acc[RB];
    #pragma unroll
    for (int r = 0; r < RB; ++r) acc[r] = make_float4(0.f, 0.f, 0.f, 0.f);

    for (int rep = 0; rep < REPEAT; ++rep) {
        #pragma unroll 4
        for (int jj = 0; jj < JW; ++jj) {
            const int    j = j0 + jj;
            const float4 m = mu4[(size_t)j * (Cc / 4)];   // global_load_dwordx4 (L2-resident)
            #pragma unroll
            for (int r = 0; r < RB; ++r) {
                const float xv = xp[r * Fc + j];          // uniform -> scalar path
                const float d0 = xv - m.x;
                const float d1 = xv - m.y;
                const float d2 = xv - m.z;
                const float d3 = xv - m.w;
                acc[r].x += fast_rsqrt(fmaf(d0, d0, 1.0f));
                acc[r].y += fast_rsqrt(fmaf(d1, d1, 1.0f));
                acc[r].z += fast_rsqrt(fmaf(d2, d2, 1.0f));
                acc[r].w += fast_rsqrt(fmaf(d3, d3, 1.0f));
            }
        }
    }

    // stage per-wave partials (contiguous b128 writes: conflict-free)
    #pragma unroll
    for (int r = 0; r < RB; ++r)
        *(float4*)&red[wv][r][lane * 4] = acc[r];
    __syncthreads();

    // each thread reduces 2 output elements across the 8 j-slice partials
    const int e = tid * 2;                        // flat [RB][Cc] index, 0..1022
    float2 s = make_float2(0.f, 0.f);
    #pragma unroll
    for (int w = 0; w < NW; ++w) {
        const float2 v = *(const float2*)&(((const float*)red[w])[e]);
        s.x += v.x; s.y += v.y;
    }

    // den per row: each wave's e-range sits inside one row (row = tid>>7)
    float p = s.x + s.y;
    #pragma unroll
    for (int off = 1; off < 64; off <<= 1)
        p += __shfl_xor(p, off, 64);
    if (lane == 0) denp[wv] = p;
    __syncthreads();

    const int   r   = tid >> 7;                   // row of this thread's elements
    const float den = denp[2 * r] + denp[2 * r + 1];
    const float rc  = fast_rcp(den);              // (5*num)/(5*den) == num/den

    float2 o = make_float2(s.x * rc, s.y * rc);
    *(float2*)&out[(size_t)b0 * Cc + e] = o;      // coalesced float2 store
}

extern "C" void kernel_launch(void* const* d_in, const int* in_sizes, int n_in,
                              void* d_out, int out_size, void* d_ws, size_t ws_size,
                              hipStream_t stream) {
    const float* x  = (const float*)d_in[0];   // (2048, 256) f32
    const float* mu = (const float*)d_in[1];   // (256, 256)  f32
    float* out = (float*)d_out;                // (2048, 256) f32

    dim3 grid(Bc / RB), block(NW * 64);        // 512 blocks x 8 waves = 4096 waves
    hipLaunchKernelGGL(clusteringLayer_77154792506116_kernel, grid, block, 0, stream,
                       x, mu, out);
}

// Round 5
// 75.980 us; speedup vs baseline: 1.8112x; 1.8112x over previous
//
#include <hip/hip_runtime.h>

typedef float        f32x2 __attribute__((ext_vector_type(2)));
typedef float        f32x4 __attribute__((ext_vector_type(4)));
typedef unsigned int u32x2 __attribute__((ext_vector_type(2)));

__device__ __forceinline__ float fast_rcp(float x) {
#if __has_builtin(__builtin_amdgcn_rcpf)
    return __builtin_amdgcn_rcpf(x);
#else
    return 1.0f / x;
#endif
}

// Packed fast inverse sqrt: bit-trick seed + 1 tuned Newton step (Kadlec).
//   y0 = bitcast(0x5F1FFFF9 - (i >> 1))
//   y1 = y0 * (1.6819147 - 0.7039522 * h * y0^2)      max rel err ~6.5e-4
// All fp ops are <2 x float> -> v_pk_mul/fma_f32 on gfx950 (2 elems/instr).
// The global 1/sqrt(2) factor of the reference cancels in num/den.
__device__ __forceinline__ f32x2 rsqrt_nr2(f32x2 h) {
    u32x2 i;
    __builtin_memcpy(&i, &h, 8);
    i = (u32x2)(0x5F1FFFF9u) - (i >> 1);         // 2x v_lshrrev + 2x v_sub (no pk int ops)
    f32x2 y;
    __builtin_memcpy(&y, &i, 8);
    const f32x2 g  = h * -0.7039522f;            // v_pk_mul_f32
    const f32x2 y2 = y * y;                      // v_pk_mul_f32
    f32x2 c = __builtin_elementwise_fma(g, y2, (f32x2)1.6819147f);  // v_pk_fma_f32
    return y * c;                                // v_pk_mul_f32
}

constexpr int Bc = 2048;    // batch
constexpr int Fc = 256;     // in_features
constexpr int Cc = 256;     // clusters
constexpr int RB = 4;       // batch rows per block
constexpr int NW = 8;       // waves per block (512 threads)
constexpr int JW = Fc / NW; // 32: j-slice per wave

// out[b,i] = num[b,i]/den[b];  num = sum_j rsqrt(1+(x[b,j]-mu[j,i])^2)  (sqrt2 cancels)
// Same R3 structure (passed + verified): block = 4 rows x 8 waves, wave = 32-j slice,
// lane = 4 consecutive clusters, LDS reduction over j-slices. Only the math changed.
__global__ __launch_bounds__(512, 4)
void clusteringLayer_77154792506116_kernel(const float* __restrict__ x,
                                           const float* __restrict__ mu,
                                           float* __restrict__ out) {
    const int tid  = threadIdx.x;
    const int wv   = tid >> 6;
    const int lane = tid & 63;
    const int b0   = blockIdx.x * RB;

    __shared__ float red[NW][RB][Cc];   // 32 KB partial nums
    __shared__ float denp[NW];          // per-wave den partials

    const int    j0   = __builtin_amdgcn_readfirstlane(wv * JW);  // SGPR
    const float* xp   = x + (size_t)b0 * Fc;                      // scalar base
    const f32x4* mu4  = (const f32x4*)mu + lane;                  // mu[j][4l..4l+3]

    f32x2 acc[RB][2];
    #pragma unroll
    for (int r = 0; r < RB; ++r) { acc[r][0] = (f32x2)0.0f; acc[r][1] = (f32x2)0.0f; }

    #pragma unroll 8
    for (int jj = 0; jj < JW; ++jj) {
        const int   j   = j0 + jj;
        const f32x4 m   = mu4[(size_t)j * (Cc / 4)];   // global_load_dwordx4 (L2/L3-resident)
        const f32x2 m01 = __builtin_shufflevector(m, m, 0, 1);
        const f32x2 m23 = __builtin_shufflevector(m, m, 2, 3);
        #pragma unroll
        for (int r = 0; r < RB; ++r) {
            const float xv = xp[r * Fc + j];           // uniform -> s_load (batched dwordx8)
            const f32x2 x2 = {xv, xv};
            const f32x2 d0 = x2 - m01;                 // v_pk_add_f32 (neg)
            const f32x2 d1 = x2 - m23;
            const f32x2 h0 = __builtin_elementwise_fma(d0, d0, (f32x2)1.0f);  // v_pk_fma
            const f32x2 h1 = __builtin_elementwise_fma(d1, d1, (f32x2)1.0f);
            acc[r][0] += rsqrt_nr2(h0);                // v_pk_add_f32 accumulate
            acc[r][1] += rsqrt_nr2(h1);
        }
    }

    // stage per-wave partials (contiguous b128 writes: conflict-free)
    #pragma unroll
    for (int r = 0; r < RB; ++r) {
        const f32x4 v = __builtin_shufflevector(acc[r][0], acc[r][1], 0, 1, 2, 3);
        *(f32x4*)&red[wv][r][lane * 4] = v;
    }
    __syncthreads();

    // each thread reduces 2 output elements across the 8 j-slice partials
    const int e = tid * 2;                        // flat [RB][Cc] index, 0..1022
    float2 s = make_float2(0.f, 0.f);
    #pragma unroll
    for (int w = 0; w < NW; ++w) {
        const float2 v = *(const float2*)&(((const float*)red[w])[e]);
        s.x += v.x; s.y += v.y;
    }

    // den per row: each wave's e-range sits inside one row (row = tid>>7)
    float p = s.x + s.y;
    #pragma unroll
    for (int off = 1; off < 64; off <<= 1)
        p += __shfl_xor(p, off, 64);
    if (lane == 0) denp[wv] = p;
    __syncthreads();

    const int   r   = tid >> 7;                   // row of this thread's elements
    const float den = denp[2 * r] + denp[2 * r + 1];
    const float rc  = fast_rcp(den);

    float2 o = make_float2(s.x * rc, s.y * rc);
    *(float2*)&out[(size_t)b0 * Cc + e] = o;      // coalesced float2 store
}

extern "C" void kernel_launch(void* const* d_in, const int* in_sizes, int n_in,
                              void* d_out, int out_size, void* d_ws, size_t ws_size,
                              hipStream_t stream) {
    const float* x  = (const float*)d_in[0];   // (2048, 256) f32
    const float* mu = (const float*)d_in[1];   // (256, 256)  f32
    float* out = (float*)d_out;                // (2048, 256) f32

    dim3 grid(Bc / RB), block(NW * 64);        // 512 blocks x 8 waves = 4096 waves
    hipLaunchKernelGGL(clusteringLayer_77154792506116_kernel, grid, block, 0, stream,
                       x, mu, out);
}

// Round 6
// 75.694 us; speedup vs baseline: 1.8180x; 1.0038x over previous
//
#include <hip/hip_runtime.h>

typedef float        f32x2 __attribute__((ext_vector_type(2)));
typedef float        f32x4 __attribute__((ext_vector_type(4)));
typedef unsigned int u32x2 __attribute__((ext_vector_type(2)));

__device__ __forceinline__ float fast_rcp(float x) {
#if __has_builtin(__builtin_amdgcn_rcpf)
    return __builtin_amdgcn_rcpf(x);
#else
    return 1.0f / x;
#endif
}

// One packed term: acc += rsqrt(1 + (m - x)^2) for 2 clusters.
// Forced VOP3P (v_pk_*_f32) via inline asm — hipcc was scalarizing the
// ext_vector version (R5 neutral). Seed: Kadlec bit trick + 1 tuned Newton
// step, max rel err ~6.5e-4 (invisible under the 3.05e-5 fp32-vs-ref floor).
// xs = {-x,-x} lives in an SGPR pair (built on the scalar pipe, free);
// kA/kB/one2 are SGPR pairs; every VOP3P uses <=1 SGPR operand.
__device__ __forceinline__ f32x2 term2(f32x2 m, f32x2 xs, f32x2 kA, f32x2 kB,
                                       f32x2 one2, f32x2 acc) {
    f32x2 d, h, g, y2, c;
    asm("v_pk_add_f32 %0, %1, %2" : "=v"(d) : "v"(m), "s"(xs));              // d = m - x
    asm("v_pk_fma_f32 %0, %1, %1, %2" : "=v"(h) : "v"(d), "s"(one2));        // h = d*d + 1
    u32x2 i; __builtin_memcpy(&i, &h, 8);
    u32x2 t = (u32x2)0x5F1FFFF9u - (i >> 1);                                  // 2x lshr + 2x sub (VOP2)
    f32x2 y; __builtin_memcpy(&y, &t, 8);
    asm("v_pk_mul_f32 %0, %1, %2" : "=v"(g) : "v"(h), "s"(kB));              // g = -0.7039522*h
    asm("v_pk_mul_f32 %0, %1, %1" : "=v"(y2) : "v"(y));                      // y2 = y*y
    asm("v_pk_fma_f32 %0, %1, %2, %3" : "=v"(c) : "v"(g), "v"(y2), "s"(kA)); // c = g*y2 + 1.6819147
    asm("v_pk_fma_f32 %0, %1, %2, %0" : "+v"(acc) : "v"(y), "v"(c));         // acc += y*c
    return acc;
}

constexpr int Bc = 2048;    // batch
constexpr int Fc = 256;     // in_features
constexpr int Cc = 256;     // clusters
constexpr int RB = 4;       // batch rows per block
constexpr int NW = 8;       // waves per block (512 threads)
constexpr int JW = Fc / NW; // 32: j-slice per wave

// out[b,i] = num[b,i]/den[b];  num = sum_j rsqrt(1+(x[b,j]-mu[j,i])^2)  (sqrt2 cancels)
// Structure identical to R3 (verified): block = 4 rows x 8 waves, wave = 32-j
// slice over all 256 clusters (4/lane), LDS reduction over j-slices.
__global__ __launch_bounds__(512, 4)
void clusteringLayer_77154792506116_kernel(const float* __restrict__ x,
                                           const float* __restrict__ mu,
                                           float* __restrict__ out) {
    const int tid  = threadIdx.x;
    const int wv   = tid >> 6;
    const int lane = tid & 63;
    const int b0   = blockIdx.x * RB;

    __shared__ float red[NW][RB][Cc];   // 32 KB partial nums
    __shared__ float denp[NW];          // per-wave den partials

    const int    j0  = __builtin_amdgcn_readfirstlane(wv * JW);  // SGPR
    const float* xp  = x + (size_t)b0 * Fc;                      // scalar base
    const f32x4* mu4 = (const f32x4*)mu + lane;                  // mu[j][4l..4l+3]

    const f32x2 kA   = { 1.6819147f,  1.6819147f};
    const f32x2 kB   = {-0.7039522f, -0.7039522f};
    const f32x2 one2 = { 1.0f, 1.0f};

    f32x2 acc[RB][2];
    #pragma unroll
    for (int r = 0; r < RB; ++r) { acc[r][0] = (f32x2)0.0f; acc[r][1] = (f32x2)0.0f; }

    #pragma unroll 8
    for (int jj = 0; jj < JW; ++jj) {
        const int   j   = j0 + jj;
        const f32x4 m   = mu4[(size_t)j * (Cc / 4)];   // global_load_dwordx4 (L2/L3-resident)
        const f32x2 m01 = __builtin_shufflevector(m, m, 0, 1);
        const f32x2 m23 = __builtin_shufflevector(m, m, 2, 3);
        #pragma unroll
        for (int r = 0; r < RB; ++r) {
            const float xn = -xp[r * Fc + j];          // uniform: s_load + s_xor (scalar pipe)
            const f32x2 xs = {xn, xn};                 // SGPR pair
            acc[r][0] = term2(m01, xs, kA, kB, one2, acc[r][0]);
            acc[r][1] = term2(m23, xs, kA, kB, one2, acc[r][1]);
        }
    }

    // stage per-wave partials (contiguous b128 writes: conflict-free)
    #pragma unroll
    for (int r = 0; r < RB; ++r) {
        const f32x4 v = __builtin_shufflevector(acc[r][0], acc[r][1], 0, 1, 2, 3);
        *(f32x4*)&red[wv][r][lane * 4] = v;
    }
    __syncthreads();

    // each thread reduces 2 output elements across the 8 j-slice partials
    const int e = tid * 2;                        // flat [RB][Cc] index, 0..1022
    float2 s = make_float2(0.f, 0.f);
    #pragma unroll
    for (int w = 0; w < NW; ++w) {
        const float2 v = *(const float2*)&(((const float*)red[w])[e]);
        s.x += v.x; s.y += v.y;
    }

    // den per row: each wave's e-range sits inside one row (row = tid>>7)
    float p = s.x + s.y;
    #pragma unroll
    for (int off = 1; off < 64; off <<= 1)
        p += __shfl_xor(p, off, 64);
    if (lane == 0) denp[wv] = p;
    __syncthreads();

    const int   r   = tid >> 7;                   // row of this thread's elements
    const float den = denp[2 * r] + denp[2 * r + 1];
    const float rc  = fast_rcp(den);

    float2 o = make_float2(s.x * rc, s.y * rc);
    *(float2*)&out[(size_t)b0 * Cc + e] = o;      // coalesced float2 store
}

extern "C" void kernel_launch(void* const* d_in, const int* in_sizes, int n_in,
                              void* d_out, int out_size, void* d_ws, size_t ws_size,
                              hipStream_t stream) {
    const float* x  = (const float*)d_in[0];   // (2048, 256) f32
    const float* mu = (const float*)d_in[1];   // (256, 256)  f32
    float* out = (float*)d_out;                // (2048, 256) f32

    dim3 grid(Bc / RB), block(NW * 64);        // 512 blocks x 8 waves = 4096 waves
    hipLaunchKernelGGL(clusteringLayer_77154792506116_kernel, grid, block, 0, stream,
                       x, mu, out);
}